// Round 9
// baseline (1229.802 us; speedup 1.0000x reference)
//
#include <hip/hip_runtime.h>
#include <hip/hip_bf16.h>

typedef short bf4 __attribute__((ext_vector_type(4)));
typedef short short8 __attribute__((ext_vector_type(8)));
typedef float f32x4 __attribute__((ext_vector_type(4)));

#define MFMA(a, b, c) __builtin_amdgcn_mfma_f32_16x16x32_bf16((a), (b), (c), 0, 0, 0)

#define NB 2
#define NS 1024
#define NHID 768
#define NHEAD 12
#define NDH 64

#define REP_QKV 4
#define REP_ATTN 20

__device__ __forceinline__ short f2bf(float x) {
    __hip_bfloat16 h = __float2bfloat16(x);
    return *reinterpret_cast<short*>(&h);
}

typedef const __attribute__((address_space(1))) void gas_t;
typedef __attribute__((address_space(3))) void las_t;
__device__ __forceinline__ void gld_lds16(const float* g, float* l) {
    __builtin_amdgcn_global_load_lds((gas_t*)g, (las_t*)l, 16, 0, 0);
}
__device__ __forceinline__ void gld_lds16s(const short* g, short* l) {
    __builtin_amdgcn_global_load_lds((gas_t*)g, (las_t*)l, 16, 0, 0);
}

// ---------------------------------------------------------------------------
// Kernel 0: convert hidden + Wq/Wk/Wv to bf16 (once).
// ---------------------------------------------------------------------------
#define NHE (2048 * 768)
#define WE  (768 * 768)
__global__ void cvt_bf16_all(
    const float* __restrict__ hidden,
    const float* __restrict__ Wq, const float* __restrict__ Wk,
    const float* __restrict__ Wv,
    short* __restrict__ Xbf, short* __restrict__ Wbf)
{
    const int base = (blockIdx.x * 256 + threadIdx.x) * 4;
    const float* src; short* dst; int off;
    if (base < NHE)               { src = hidden; dst = Xbf;          off = base; }
    else if (base < NHE + WE)     { src = Wq;     dst = Wbf;          off = base - NHE; }
    else if (base < NHE + 2 * WE) { src = Wk;     dst = Wbf + WE;     off = base - NHE - WE; }
    else                          { src = Wv;     dst = Wbf + 2 * WE; off = base - NHE - 2 * WE; }
    f32x4 v = *reinterpret_cast<const f32x4*>(src + off);
    bf4 r;
    r[0] = f2bf(v[0]); r[1] = f2bf(v[1]); r[2] = f2bf(v[2]); r[3] = f2bf(v[3]);
    *reinterpret_cast<bf4*>(dst + off) = r;
}

// ---------------------------------------------------------------------------
// Shared GEMM body for qkv (BM=128 BN=64 BK=64, staged, 4 waves).
// EP=0: real epilogue (Q,K row-major; V transposed scatter).
// EP=1: probe epilogue (Q,K,V ALL row-major -> isolates VT-scatter cost).
// ---------------------------------------------------------------------------
template <int EP>
__device__ __forceinline__ void qkv_body(
    const short* __restrict__ Xbf, const short* __restrict__ Wbf,
    const float* __restrict__ bq, const float* __restrict__ bk,
    const float* __restrict__ bv,
    short* __restrict__ Qo, short* __restrict__ Ko, short* __restrict__ VTo,
    short (*Alds)[128 * 64], short (*Blds)[64 * 64])
{
    const int lane = threadIdx.x & 63;
    const int wave = threadIdx.x >> 6;
    const int lg = lane >> 4, lr = lane & 15;

    const int m0 = blockIdx.x * 128;
    const int n0 = blockIdx.y * 64;
    const int proj = n0 / NHID;
    const int ncol0 = n0 % NHID;
    const float* bias = proj == 0 ? bq : (proj == 1 ? bk : bv);

    f32x4 acc[2][4];
    #pragma unroll
    for (int mm = 0; mm < 2; ++mm)
        #pragma unroll
        for (int s = 0; s < 4; ++s) acc[mm][s] = (f32x4){0.f, 0.f, 0.f, 0.f};

    auto stage = [&](int t, int buf) {
        const int k0 = t * 64;
        #pragma unroll
        for (int p = 0; p < 4; ++p) {
            const int op = wave * 4 + p;
            const int unit = op * 64 + lane;
            const int r = unit >> 3, u = unit & 7;
            const int g = u ^ (r & 7);
            gld_lds16s(Xbf + (size_t)(m0 + r) * NHID + k0 + g * 8,
                       &Alds[buf][op * 512]);
        }
        #pragma unroll
        for (int p = 0; p < 2; ++p) {
            const int op = wave * 2 + p;
            const int unit = op * 64 + lane;
            const int r = unit >> 3, u = unit & 7;
            const int g = u ^ (r & 7);
            gld_lds16s(Wbf + (size_t)(n0 + r) * NHID + k0 + g * 8,
                       &Blds[buf][op * 512]);
        }
    };

    auto compute = [&](int buf) {
        #pragma unroll
        for (int kk = 0; kk < 2; ++kk) {
            const int U = kk * 4 + lg;
            short8 a[2];
            #pragma unroll
            for (int mm = 0; mm < 2; ++mm) {
                const int R = wave * 32 + mm * 16 + lr;
                a[mm] = *reinterpret_cast<const short8*>(
                    &Alds[buf][(R * 8 + (U ^ (R & 7))) * 8]);
            }
            #pragma unroll
            for (int s = 0; s < 4; ++s) {
                const int R = s * 16 + lr;
                short8 b = *reinterpret_cast<const short8*>(
                    &Blds[buf][(R * 8 + (U ^ (R & 7))) * 8]);
                acc[0][s] = MFMA(a[0], b, acc[0][s]);
                acc[1][s] = MFMA(a[1], b, acc[1][s]);
            }
        }
    };

    stage(0, 0);
    #pragma unroll 2
    for (int t = 0; t < 12; ++t) {
        const int buf = t & 1;
        asm volatile("s_waitcnt vmcnt(0)" ::: "memory");
        __syncthreads();
        if (t < 11) stage(t + 1, buf ^ 1);
        compute(buf);
    }

    #pragma unroll
    for (int mm = 0; mm < 2; ++mm) {
        #pragma unroll
        for (int s = 0; s < 4; ++s) {
            const int ncol = ncol0 + s * 16 + lr;
            const float badd = bias[ncol];
            #pragma unroll
            for (int r = 0; r < 4; ++r) {
                const int m = m0 + wave * 32 + mm * 16 + lg * 4 + r;
                const short v16 = f2bf(acc[mm][s][r] + badd);
                if (proj == 0) {
                    Qo[(size_t)m * NHID + ncol] = v16;
                } else if (proj == 1) {
                    Ko[(size_t)m * NHID + ncol] = v16;
                } else {
                    if (EP == 0) {
                        const int b = m >> 10, ss = m & 1023;
                        const int h = ncol >> 6, dd = ncol & 63;
                        VTo[(((size_t)(b * NHEAD + h) * NDH + dd) << 10) + ss] = v16;
                    } else {
                        VTo[(size_t)m * NHID + ncol] = v16;   // row-major probe
                    }
                }
            }
        }
    }
}

__global__ __launch_bounds__(256, 3) void qkv_gemm(
    const short* __restrict__ Xbf, const short* __restrict__ Wbf,
    const float* __restrict__ bq, const float* __restrict__ bk,
    const float* __restrict__ bv,
    short* __restrict__ Qo, short* __restrict__ Ko, short* __restrict__ VTo)
{
    __shared__ short Alds[2][128 * 64];
    __shared__ short Blds[2][64 * 64];
    for (int rep = 0; rep < REP_QKV; ++rep) {
        qkv_body<0>(Xbf, Wbf, bq, bk, bv, Qo, Ko, VTo, Alds, Blds);
        __syncthreads();
    }
}

__global__ __launch_bounds__(256, 3) void qkv_probe(
    const short* __restrict__ Xbf, const short* __restrict__ Wbf,
    const float* __restrict__ bq, const float* __restrict__ bk,
    const float* __restrict__ bv,
    short* __restrict__ Qo, short* __restrict__ Ko, short* __restrict__ VTo)
{
    __shared__ short Alds[2][128 * 64];
    __shared__ short Blds[2][64 * 64];
    for (int rep = 0; rep < REP_QKV; ++rep) {
        qkv_body<1>(Xbf, Wbf, bq, bk, bv, Qo, Ko, VTo, Alds, Blds);
        __syncthreads();
    }
}

// ---------------------------------------------------------------------------
// Kernel 2: bias GEMM (measured at combined-traffic roofline, ~97us).
// ---------------------------------------------------------------------------
__global__ __launch_bounds__(256, 2) void bias_gemm(
    const short* __restrict__ Q,
    const float* __restrict__ bbox,
    float* __restrict__ biasO)
{
    const int lane = threadIdx.x & 63;
    const int wave = threadIdx.x >> 6;
    const int lg = lane >> 4, lr = lane & 15;
    const int i = blockIdx.x;
    const int jq = wave * 256;

    __shared__ float lds[4][2][2048];

    short8 qa[2][2];
    #pragma unroll
    for (int b2 = 0; b2 < 2; ++b2)
        #pragma unroll
        for (int kk = 0; kk < 2; ++kk)
            qa[b2][kk] = *reinterpret_cast<const short8*>(
                Q + ((size_t)(b2 * NS) + i) * NHID + lr * 64 + kk * 32 + lg * 8);

    const int r_half = lane >> 5;
    const int u_lin = lane & 31;

    auto stage = [&](int t, int buf) {
        const int j0 = jq + t * 16;
        float* dst = &lds[wave][buf][0];
        #pragma unroll
        for (int w = 0; w < 8; ++w) {
            const int r = 2 * w + r_half;
            const int u = u_lin ^ (r & 7);
            const float* src = bbox + (size_t)(i * NS + j0 + r) * 128 + u * 4;
            gld_lds16(src, dst + w * 256);
        }
    };

    auto compute = [&](int t, int buf) {
        const float* tile = &lds[wave][buf][0];
        const int j0 = jq + t * 16;
        const int x = lr & 7;
        #pragma unroll
        for (int b2 = 0; b2 < 2; ++b2) {
            f32x4 c = (f32x4){0.f, 0.f, 0.f, 0.f};
            #pragma unroll
            for (int kk = 0; kk < 2; ++kk) {
                const int q0 = b2 * 16 + kk * 8 + lg * 2;
                f32x4 ca = *reinterpret_cast<const f32x4*>(tile + (size_t)(lr * 32 + ((q0)     ^ x)) * 4);
                f32x4 cb = *reinterpret_cast<const f32x4*>(tile + (size_t)(lr * 32 + ((q0 + 1) ^ x)) * 4);
                short8 bf;
                bf[0] = f2bf(ca[0]); bf[1] = f2bf(ca[1]); bf[2] = f2bf(ca[2]); bf[3] = f2bf(ca[3]);
                bf[4] = f2bf(cb[0]); bf[5] = f2bf(cb[1]); bf[6] = f2bf(cb[2]); bf[7] = f2bf(cb[3]);
                c = MFMA(qa[b2][kk], bf, c);
            }
            if (lg < 3) {
                #pragma unroll
                for (int r = 0; r < 4; ++r) {
                    const int n = lg * 4 + r;
                    biasO[((size_t)(b2 * NHEAD + n) * NS + i) * NS + j0 + lr] = c[r];
                }
            }
        }
    };

    stage(0, 0);
    for (int t = 0; t < 16; ++t) {
        const int buf = t & 1;
        asm volatile("s_waitcnt lgkmcnt(0)" ::: "memory");
        if (t < 15) stage(t + 1, buf ^ 1);
        if (t == 0 || t == 15) asm volatile("s_waitcnt vmcnt(8)"  ::: "memory");
        else                   asm volatile("s_waitcnt vmcnt(16)" ::: "memory");
        compute(t, buf);
    }
}

// ---------------------------------------------------------------------------
// Kernel 3: attention (repped x20 for counters).
// ---------------------------------------------------------------------------
__global__ __launch_bounds__(256, 4) void attn2(
    const short* __restrict__ Q,
    const short* __restrict__ K,
    const short* __restrict__ VT,
    const float* __restrict__ biasO,
    const float* __restrict__ mask,
    float* __restrict__ out)
{
    const int lane = threadIdx.x & 63;
    const int wave = threadIdx.x >> 6;
    const int lg = lane >> 4, lr = lane & 15;
    const int i0 = blockIdx.x * 16;
    const int bh = blockIdx.y;
    const int b = bh / NHEAD, h = bh % NHEAD;
    const int jq = wave * 256;

    __shared__ short plds[4][16][40];
    __shared__ float numlds[4][16][68];
    __shared__ float denlds[4][16];

    for (int rep = 0; rep < REP_ATTN; ++rep) {
        __syncthreads();

        short8 qa[2];
        #pragma unroll
        for (int kk = 0; kk < 2; ++kk)
            qa[kk] = *reinterpret_cast<const short8*>(
                Q + ((size_t)(b * NS) + i0 + lr) * NHID + h * 64 + kk * 32 + lg * 8);

        f32x4 ctx[4];
        #pragma unroll
        for (int dt = 0; dt < 4; ++dt) ctx[dt] = (f32x4){0.f, 0.f, 0.f, 0.f};
        f32x4 den = (f32x4){0.f, 0.f, 0.f, 0.f};

        #pragma unroll 2
        for (int t = 0; t < 8; ++t) {
            const int j0 = jq + t * 32;
            f32x4 sc[2];
            #pragma unroll
            for (int s = 0; s < 2; ++s) {
                f32x4 c = (f32x4){0.f, 0.f, 0.f, 0.f};
                #pragma unroll
                for (int kk = 0; kk < 2; ++kk) {
                    short8 kf = *reinterpret_cast<const short8*>(
                        K + ((size_t)(b * NS) + j0 + s * 16 + lr) * NHID + h * 64 + kk * 32 + lg * 8);
                    c = MFMA(qa[kk], kf, c);
                }
                sc[s] = c;
            }
            const float mk0 = mask[b * NS + j0 + lr];
            const float mk1 = mask[b * NS + j0 + 16 + lr];
            #pragma unroll
            for (int s = 0; s < 2; ++s) {
                const float mk = s == 0 ? mk0 : mk1;
                #pragma unroll
                for (int r = 0; r < 4; ++r) {
                    const int i = i0 + lg * 4 + r;
                    const float bb = biasO[((size_t)(b * NHEAD + h) * NS + i) * NS + j0 + s * 16 + lr];
                    sc[s][r] = __expf((sc[s][r] + bb) * 0.125f + mk);
                }
            }
            den += sc[0] + sc[1];

            #pragma unroll
            for (int s = 0; s < 2; ++s)
                #pragma unroll
                for (int r = 0; r < 4; ++r)
                    plds[wave][lg * 4 + r][s * 16 + lr] = f2bf(sc[s][r]);
            asm volatile("" ::: "memory");
            short8 pa = *reinterpret_cast<const short8*>(&plds[wave][lr][lg * 8]);
            asm volatile("" ::: "memory");

            #pragma unroll
            for (int dt = 0; dt < 4; ++dt) {
                short8 vf = *reinterpret_cast<const short8*>(
                    VT + ((size_t)(b * NHEAD + h) * NDH + dt * 16 + lr) * NS + j0 + lg * 8);
                ctx[dt] = MFMA(pa, vf, ctx[dt]);
            }
        }

        #pragma unroll
        for (int w = 1; w < 16; w <<= 1) {
            f32x4 o;
            #pragma unroll
            for (int r = 0; r < 4; ++r) o[r] = __shfl_xor(den[r], w, 64);
            den += o;
        }

        #pragma unroll
        for (int dt = 0; dt < 4; ++dt)
            #pragma unroll
            for (int r = 0; r < 4; ++r)
                numlds[wave][lg * 4 + r][dt * 16 + lr] = ctx[dt][r];
        if (lr == 0) {
            #pragma unroll
            for (int r = 0; r < 4; ++r) denlds[wave][lg * 4 + r] = den[r];
        }
        __syncthreads();

        const int ti = threadIdx.x >> 4;
        const int tc = (threadIdx.x & 15) * 4;
        f32x4 n = *reinterpret_cast<const f32x4*>(&numlds[0][ti][tc]);
        n += *reinterpret_cast<const f32x4*>(&numlds[1][ti][tc]);
        n += *reinterpret_cast<const f32x4*>(&numlds[2][ti][tc]);
        n += *reinterpret_cast<const f32x4*>(&numlds[3][ti][tc]);
        const float dd = denlds[0][ti] + denlds[1][ti] + denlds[2][ti] + denlds[3][ti];
        const float inv = 1.0f / dd;
        f32x4 o = n * inv;
        *reinterpret_cast<f32x4*>(out + ((size_t)(b * NS) + i0 + ti) * NHID + h * 64 + tc) = o;
    }
}

extern "C" void kernel_launch(void* const* d_in, const int* in_sizes, int n_in,
                              void* d_out, int out_size, void* d_ws, size_t ws_size,
                              hipStream_t stream) {
    (void)in_sizes; (void)n_in; (void)out_size; (void)ws_size;
    const float* hidden = (const float*)d_in[0];
    const float* bbox   = (const float*)d_in[1];
    const float* mask   = (const float*)d_in[2];
    const float* Wq = (const float*)d_in[3]; const float* bq = (const float*)d_in[4];
    const float* Wk = (const float*)d_in[5]; const float* bk = (const float*)d_in[6];
    const float* Wv = (const float*)d_in[7]; const float* bv = (const float*)d_in[8];
    float* out = (float*)d_out;

    char* ws = (char*)d_ws;
    const size_t qkv_bytes = (size_t)NB * NS * NHID * sizeof(short);
    short* Qw  = (short*)ws;
    short* Kw  = (short*)(ws + qkv_bytes);
    short* VTw = (short*)(ws + 2 * qkv_bytes);
    float* biasW = (float*)(ws + 3 * qkv_bytes);
    const size_t bias_bytes = (size_t)NB * NHEAD * NS * NS * sizeof(float);
    short* Xbf = (short*)(ws + 3 * qkv_bytes + bias_bytes);
    short* Wbf = Xbf + (size_t)2048 * NHID;
    // probe scratch (outputs unused for correctness)
    short* Qp = (short*)(ws + 120 * 1024 * 1024);
    short* Kp = Qp + (size_t)2048 * NHID;
    short* Vp = Kp + (size_t)2048 * NHID;

    const int cvt_total = (NHE + 3 * WE) / 4;
    cvt_bf16_all<<<cvt_total / 256, 256, 0, stream>>>(hidden, Wq, Wk, Wv, Xbf, Wbf);

    dim3 gp(16, 36);
    qkv_gemm<<<gp, 256, 0, stream>>>(Xbf, Wbf, bq, bk, bv, Qw, Kw, VTw);
    qkv_probe<<<gp, 256, 0, stream>>>(Xbf, Wbf, bq, bk, bv, Qp, Kp, Vp);

    bias_gemm<<<NS, 256, 0, stream>>>(Qw, bbox, biasW);

    dim3 ga(NS / 16, NB * NHEAD);
    attn2<<<ga, 256, 0, stream>>>(Qw, Kw, VTw, biasW, mask, out);
}

// Round 10
// 223.883 us; speedup vs baseline: 5.4931x; 5.4931x over previous
//
#include <hip/hip_runtime.h>
#include <hip/hip_bf16.h>

typedef short bf4 __attribute__((ext_vector_type(4)));
typedef short short8 __attribute__((ext_vector_type(8)));
typedef float f32x4 __attribute__((ext_vector_type(4)));

#define MFMA(a, b, c) __builtin_amdgcn_mfma_f32_16x16x32_bf16((a), (b), (c), 0, 0, 0)

#define NB 2
#define NS 1024
#define NHID 768
#define NHEAD 12
#define NDH 64

__device__ __forceinline__ short f2bf(float x) {
    __hip_bfloat16 h = __float2bfloat16(x);
    return *reinterpret_cast<short*>(&h);
}

typedef const __attribute__((address_space(1))) void gas_t;
typedef __attribute__((address_space(3))) void las_t;
__device__ __forceinline__ void gld_lds16(const float* g, float* l) {
    __builtin_amdgcn_global_load_lds((gas_t*)g, (las_t*)l, 16, 0, 0);
}
__device__ __forceinline__ void gld_lds16s(const short* g, short* l) {
    __builtin_amdgcn_global_load_lds((gas_t*)g, (las_t*)l, 16, 0, 0);
}

// ---------------------------------------------------------------------------
// Kernel 0: convert hidden + Wq/Wk/Wv to bf16 (once).
// ---------------------------------------------------------------------------
#define NHE (2048 * 768)
#define WE  (768 * 768)
__global__ void cvt_bf16_all(
    const float* __restrict__ hidden,
    const float* __restrict__ Wq, const float* __restrict__ Wk,
    const float* __restrict__ Wv,
    short* __restrict__ Xbf, short* __restrict__ Wbf)
{
    const int base = (blockIdx.x * 256 + threadIdx.x) * 4;
    const float* src; short* dst; int off;
    if (base < NHE)               { src = hidden; dst = Xbf;          off = base; }
    else if (base < NHE + WE)     { src = Wq;     dst = Wbf;          off = base - NHE; }
    else if (base < NHE + 2 * WE) { src = Wk;     dst = Wbf + WE;     off = base - NHE - WE; }
    else                          { src = Wv;     dst = Wbf + 2 * WE; off = base - NHE - 2 * WE; }
    f32x4 v = *reinterpret_cast<const f32x4*>(src + off);
    bf4 r;
    r[0] = f2bf(v[0]); r[1] = f2bf(v[1]); r[2] = f2bf(v[2]); r[3] = f2bf(v[3]);
    *reinterpret_cast<bf4*>(dst + off) = r;
}

// ---------------------------------------------------------------------------
// Kernel 1: QKV GEMM, LDS-staged (R7 version).
// ---------------------------------------------------------------------------
__global__ __launch_bounds__(256, 3) void qkv_gemm(
    const short* __restrict__ Xbf, const short* __restrict__ Wbf,
    const float* __restrict__ bq, const float* __restrict__ bk,
    const float* __restrict__ bv,
    short* __restrict__ Qo, short* __restrict__ Ko, short* __restrict__ VTo)
{
    const int lane = threadIdx.x & 63;
    const int wave = threadIdx.x >> 6;
    const int lg = lane >> 4, lr = lane & 15;

    const int m0 = blockIdx.x * 128;
    const int n0 = blockIdx.y * 64;
    const int proj = n0 / NHID;
    const int ncol0 = n0 % NHID;
    const float* bias = proj == 0 ? bq : (proj == 1 ? bk : bv);

    __shared__ short Alds[2][128 * 64];
    __shared__ short Blds[2][64 * 64];

    f32x4 acc[2][4];
    #pragma unroll
    for (int mm = 0; mm < 2; ++mm)
        #pragma unroll
        for (int s = 0; s < 4; ++s) acc[mm][s] = (f32x4){0.f, 0.f, 0.f, 0.f};

    auto stage = [&](int t, int buf) {
        const int k0 = t * 64;
        #pragma unroll
        for (int p = 0; p < 4; ++p) {
            const int op = wave * 4 + p;
            const int unit = op * 64 + lane;
            const int r = unit >> 3, u = unit & 7;
            const int g = u ^ (r & 7);
            gld_lds16s(Xbf + (size_t)(m0 + r) * NHID + k0 + g * 8,
                       &Alds[buf][op * 512]);
        }
        #pragma unroll
        for (int p = 0; p < 2; ++p) {
            const int op = wave * 2 + p;
            const int unit = op * 64 + lane;
            const int r = unit >> 3, u = unit & 7;
            const int g = u ^ (r & 7);
            gld_lds16s(Wbf + (size_t)(n0 + r) * NHID + k0 + g * 8,
                       &Blds[buf][op * 512]);
        }
    };

    auto compute = [&](int buf) {
        #pragma unroll
        for (int kk = 0; kk < 2; ++kk) {
            const int U = kk * 4 + lg;
            short8 a[2];
            #pragma unroll
            for (int mm = 0; mm < 2; ++mm) {
                const int R = wave * 32 + mm * 16 + lr;
                a[mm] = *reinterpret_cast<const short8*>(
                    &Alds[buf][(R * 8 + (U ^ (R & 7))) * 8]);
            }
            #pragma unroll
            for (int s = 0; s < 4; ++s) {
                const int R = s * 16 + lr;
                short8 b = *reinterpret_cast<const short8*>(
                    &Blds[buf][(R * 8 + (U ^ (R & 7))) * 8]);
                acc[0][s] = MFMA(a[0], b, acc[0][s]);
                acc[1][s] = MFMA(a[1], b, acc[1][s]);
            }
        }
    };

    stage(0, 0);
    #pragma unroll 2
    for (int t = 0; t < 12; ++t) {
        const int buf = t & 1;
        asm volatile("s_waitcnt vmcnt(0)" ::: "memory");
        __syncthreads();
        if (t < 11) stage(t + 1, buf ^ 1);
        compute(buf);
    }

    #pragma unroll
    for (int mm = 0; mm < 2; ++mm) {
        #pragma unroll
        for (int s = 0; s < 4; ++s) {
            const int ncol = ncol0 + s * 16 + lr;
            const float badd = bias[ncol];
            #pragma unroll
            for (int r = 0; r < 4; ++r) {
                const int m = m0 + wave * 32 + mm * 16 + lg * 4 + r;
                const short v16 = f2bf(acc[mm][s][r] + badd);
                if (proj == 0) {
                    Qo[(size_t)m * NHID + ncol] = v16;
                } else if (proj == 1) {
                    Ko[(size_t)m * NHID + ncol] = v16;
                } else {
                    const int b = m >> 10, ss = m & 1023;
                    const int h = ncol >> 6, dd = ncol & 63;
                    VTo[(((size_t)(b * NHEAD + h) * NDH + dd) << 10) + ss] = v16;
                }
            }
        }
    }
}

// ---------------------------------------------------------------------------
// Kernel 2: bias GEMM (BW-roofline structure). NOW: outputs bf16, pre-scaled
// by 1/8 with attention_mask folded in:  bias' = (q·bbox)*0.125 + mask[b,j].
// ---------------------------------------------------------------------------
__global__ __launch_bounds__(256, 2) void bias_gemm(
    const short* __restrict__ Q,
    const float* __restrict__ bbox,
    const float* __restrict__ mask,
    short* __restrict__ biasH)        // (2,12,1024,1024) bf16
{
    const int lane = threadIdx.x & 63;
    const int wave = threadIdx.x >> 6;
    const int lg = lane >> 4, lr = lane & 15;
    const int i = blockIdx.x;
    const int jq = wave * 256;

    __shared__ float lds[4][2][2048];

    short8 qa[2][2];
    #pragma unroll
    for (int b2 = 0; b2 < 2; ++b2)
        #pragma unroll
        for (int kk = 0; kk < 2; ++kk)
            qa[b2][kk] = *reinterpret_cast<const short8*>(
                Q + ((size_t)(b2 * NS) + i) * NHID + lr * 64 + kk * 32 + lg * 8);

    const int r_half = lane >> 5;
    const int u_lin = lane & 31;

    auto stage = [&](int t, int buf) {
        const int j0 = jq + t * 16;
        float* dst = &lds[wave][buf][0];
        #pragma unroll
        for (int w = 0; w < 8; ++w) {
            const int r = 2 * w + r_half;
            const int u = u_lin ^ (r & 7);
            const float* src = bbox + (size_t)(i * NS + j0 + r) * 128 + u * 4;
            gld_lds16(src, dst + w * 256);
        }
    };

    auto compute = [&](int t, int buf) {
        const float* tile = &lds[wave][buf][0];
        const int j0 = jq + t * 16;
        const int x = lr & 7;
        #pragma unroll
        for (int b2 = 0; b2 < 2; ++b2) {
            const float mk = mask[b2 * NS + j0 + lr];
            f32x4 c = (f32x4){0.f, 0.f, 0.f, 0.f};
            #pragma unroll
            for (int kk = 0; kk < 2; ++kk) {
                const int q0 = b2 * 16 + kk * 8 + lg * 2;
                f32x4 ca = *reinterpret_cast<const f32x4*>(tile + (size_t)(lr * 32 + ((q0)     ^ x)) * 4);
                f32x4 cb = *reinterpret_cast<const f32x4*>(tile + (size_t)(lr * 32 + ((q0 + 1) ^ x)) * 4);
                short8 bf;
                bf[0] = f2bf(ca[0]); bf[1] = f2bf(ca[1]); bf[2] = f2bf(ca[2]); bf[3] = f2bf(ca[3]);
                bf[4] = f2bf(cb[0]); bf[5] = f2bf(cb[1]); bf[6] = f2bf(cb[2]); bf[7] = f2bf(cb[3]);
                c = MFMA(qa[b2][kk], bf, c);
            }
            if (lg < 3) {
                #pragma unroll
                for (int r = 0; r < 4; ++r) {
                    const int n = lg * 4 + r;
                    biasH[((size_t)(b2 * NHEAD + n) * NS + i) * NS + j0 + lr] =
                        f2bf(c[r] * 0.125f + mk);
                }
            }
        }
    };

    stage(0, 0);
    for (int t = 0; t < 16; ++t) {
        const int buf = t & 1;
        asm volatile("s_waitcnt lgkmcnt(0)" ::: "memory");
        if (t < 15) stage(t + 1, buf ^ 1);
        if (t == 0 || t == 15) asm volatile("s_waitcnt vmcnt(8)"  ::: "memory");
        else                   asm volatile("s_waitcnt vmcnt(16)" ::: "memory");
        compute(t, buf);
    }
}

// ---------------------------------------------------------------------------
// Kernel 3: attention, register double-buffered (prefetch t+1's K/V/bias
// while computing t; static buffers A/B — no dynamic indexing).
// score = qk*0.125 + bias'  (bias' already has mask + 1/8 scale folded).
// ---------------------------------------------------------------------------
__global__ __launch_bounds__(256, 2) void attn2(
    const short* __restrict__ Q,
    const short* __restrict__ K,
    const short* __restrict__ VT,
    const short* __restrict__ biasH,
    float* __restrict__ out)
{
    const int lane = threadIdx.x & 63;
    const int wave = threadIdx.x >> 6;
    const int lg = lane >> 4, lr = lane & 15;
    const int i0 = blockIdx.x * 16;
    const int bh = blockIdx.y;
    const int b = bh / NHEAD, h = bh % NHEAD;
    const int jq = wave * 256;

    __shared__ short plds[4][16][40];
    __shared__ float numlds[4][16][68];
    __shared__ float denlds[4][16];

    short8 qa[2];
    #pragma unroll
    for (int kk = 0; kk < 2; ++kk)
        qa[kk] = *reinterpret_cast<const short8*>(
            Q + ((size_t)(b * NS) + i0 + lr) * NHID + h * 64 + kk * 32 + lg * 8);

    const short* Kb = K + (size_t)b * NS * NHID + h * 64;
    const short* Vb = VT + (size_t)(b * NHEAD + h) * NDH * NS;
    const short* Bb = biasH + ((size_t)(b * NHEAD + h) * NS + i0) * NS;

    f32x4 ctx[4];
    #pragma unroll
    for (int dt = 0; dt < 4; ++dt) ctx[dt] = (f32x4){0.f, 0.f, 0.f, 0.f};
    f32x4 den = (f32x4){0.f, 0.f, 0.f, 0.f};

    short8 kfA[4], vfA[4]; unsigned short bvA[8];
    short8 kfB[4], vfB[4]; unsigned short bvB[8];

    auto load = [&](int t, short8* kf, short8* vf, unsigned short* bv) {
        const int j0 = jq + t * 32;
        #pragma unroll
        for (int s = 0; s < 2; ++s)
            #pragma unroll
            for (int kk = 0; kk < 2; ++kk)
                kf[s * 2 + kk] = *reinterpret_cast<const short8*>(
                    Kb + (size_t)(j0 + s * 16 + lr) * NHID + kk * 32 + lg * 8);
        #pragma unroll
        for (int dt = 0; dt < 4; ++dt)
            vf[dt] = *reinterpret_cast<const short8*>(
                Vb + (size_t)(dt * 16 + lr) * NS + j0 + lg * 8);
        #pragma unroll
        for (int s = 0; s < 2; ++s)
            #pragma unroll
            for (int r = 0; r < 4; ++r)
                bv[s * 4 + r] = *reinterpret_cast<const unsigned short*>(
                    Bb + (size_t)(lg * 4 + r) * NS + j0 + s * 16 + lr);
    };

    auto compute = [&](const short8* kf, const short8* vf, const unsigned short* bv) {
        f32x4 sc[2];
        #pragma unroll
        for (int s = 0; s < 2; ++s) {
            f32x4 c = (f32x4){0.f, 0.f, 0.f, 0.f};
            c = MFMA(qa[0], kf[s * 2 + 0], c);
            c = MFMA(qa[1], kf[s * 2 + 1], c);
            sc[s] = c;
        }
        #pragma unroll
        for (int s = 0; s < 2; ++s)
            #pragma unroll
            for (int r = 0; r < 4; ++r) {
                const unsigned int u = (unsigned int)bv[s * 4 + r] << 16;
                float bb;
                __builtin_memcpy(&bb, &u, 4);
                sc[s][r] = __expf(sc[s][r] * 0.125f + bb);
            }
        den += sc[0] + sc[1];

        #pragma unroll
        for (int s = 0; s < 2; ++s)
            #pragma unroll
            for (int r = 0; r < 4; ++r)
                plds[wave][lg * 4 + r][s * 16 + lr] = f2bf(sc[s][r]);
        asm volatile("" ::: "memory");
        short8 pa = *reinterpret_cast<const short8*>(&plds[wave][lr][lg * 8]);
        asm volatile("" ::: "memory");

        #pragma unroll
        for (int dt = 0; dt < 4; ++dt) ctx[dt] = MFMA(pa, vf[dt], ctx[dt]);
    };

    load(0, kfA, vfA, bvA);
    #pragma unroll
    for (int tp = 0; tp < 4; ++tp) {
        const int t = tp * 2;
        if (t + 1 < 8) load(t + 1, kfB, vfB, bvB);
        compute(kfA, vfA, bvA);
        if (t + 2 < 8) load(t + 2, kfA, vfA, bvA);
        compute(kfB, vfB, bvB);
    }

    #pragma unroll
    for (int w = 1; w < 16; w <<= 1) {
        f32x4 o;
        #pragma unroll
        for (int r = 0; r < 4; ++r) o[r] = __shfl_xor(den[r], w, 64);
        den += o;
    }

    #pragma unroll
    for (int dt = 0; dt < 4; ++dt)
        #pragma unroll
        for (int r = 0; r < 4; ++r)
            numlds[wave][lg * 4 + r][dt * 16 + lr] = ctx[dt][r];
    if (lr == 0) {
        #pragma unroll
        for (int r = 0; r < 4; ++r) denlds[wave][lg * 4 + r] = den[r];
    }
    __syncthreads();

    const int ti = threadIdx.x >> 4;
    const int tc = (threadIdx.x & 15) * 4;
    f32x4 n = *reinterpret_cast<const f32x4*>(&numlds[0][ti][tc]);
    n += *reinterpret_cast<const f32x4*>(&numlds[1][ti][tc]);
    n += *reinterpret_cast<const f32x4*>(&numlds[2][ti][tc]);
    n += *reinterpret_cast<const f32x4*>(&numlds[3][ti][tc]);
    const float dd = denlds[0][ti] + denlds[1][ti] + denlds[2][ti] + denlds[3][ti];
    const float inv = 1.0f / dd;
    f32x4 o = n * inv;
    *reinterpret_cast<f32x4*>(out + ((size_t)(b * NS) + i0 + ti) * NHID + h * 64 + tc) = o;
}

extern "C" void kernel_launch(void* const* d_in, const int* in_sizes, int n_in,
                              void* d_out, int out_size, void* d_ws, size_t ws_size,
                              hipStream_t stream) {
    (void)in_sizes; (void)n_in; (void)out_size; (void)ws_size;
    const float* hidden = (const float*)d_in[0];
    const float* bbox   = (const float*)d_in[1];
    const float* mask   = (const float*)d_in[2];
    const float* Wq = (const float*)d_in[3]; const float* bq = (const float*)d_in[4];
    const float* Wk = (const float*)d_in[5]; const float* bk = (const float*)d_in[6];
    const float* Wv = (const float*)d_in[7]; const float* bv = (const float*)d_in[8];
    float* out = (float*)d_out;

    char* ws = (char*)d_ws;
    const size_t qkv_bytes = (size_t)NB * NS * NHID * sizeof(short);   // 3 MB each
    short* Qw  = (short*)ws;
    short* Kw  = (short*)(ws + qkv_bytes);
    short* VTw = (short*)(ws + 2 * qkv_bytes);
    short* biasH = (short*)(ws + 3 * qkv_bytes);                       // 50.3 MB bf16
    const size_t bias_bytes = (size_t)NB * NHEAD * NS * NS * sizeof(short);
    short* Xbf = (short*)(ws + 3 * qkv_bytes + bias_bytes);
    short* Wbf = Xbf + (size_t)2048 * NHID;

    const int cvt_total = (NHE + 3 * WE) / 4;
    cvt_bf16_all<<<cvt_total / 256, 256, 0, stream>>>(hidden, Wq, Wk, Wv, Xbf, Wbf);

    dim3 gp(16, 36);
    qkv_gemm<<<gp, 256, 0, stream>>>(Xbf, Wbf, bq, bk, bv, Qw, Kw, VTw);

    bias_gemm<<<NS, 256, 0, stream>>>(Qw, bbox, mask, biasH);

    dim3 ga(NS / 16, NB * NHEAD);
    attn2<<<ga, 256, 0, stream>>>(Qw, Kw, VTw, biasH, out);
}

// Round 11
// 223.030 us; speedup vs baseline: 5.5141x; 1.0038x over previous
//
#include <hip/hip_runtime.h>
#include <hip/hip_bf16.h>

typedef short bf4 __attribute__((ext_vector_type(4)));
typedef short short8 __attribute__((ext_vector_type(8)));
typedef float f32x4 __attribute__((ext_vector_type(4)));

#define MFMA(a, b, c) __builtin_amdgcn_mfma_f32_16x16x32_bf16((a), (b), (c), 0, 0, 0)

#define NB 2
#define NS 1024
#define NHID 768
#define NHEAD 12
#define NDH 64

__device__ __forceinline__ short f2bf(float x) {
    __hip_bfloat16 h = __float2bfloat16(x);
    return *reinterpret_cast<short*>(&h);
}

typedef const __attribute__((address_space(1))) void gas_t;
typedef __attribute__((address_space(3))) void las_t;
__device__ __forceinline__ void gld_lds16(const float* g, float* l) {
    __builtin_amdgcn_global_load_lds((gas_t*)g, (las_t*)l, 16, 0, 0);
}
__device__ __forceinline__ void gld_lds16s(const short* g, short* l) {
    __builtin_amdgcn_global_load_lds((gas_t*)g, (las_t*)l, 16, 0, 0);
}

// ---------------------------------------------------------------------------
// Kernel 0: convert hidden + Wq/Wk/Wv to bf16 (once).
// ---------------------------------------------------------------------------
#define NHE (2048 * 768)
#define WE  (768 * 768)
__global__ void cvt_bf16_all(
    const float* __restrict__ hidden,
    const float* __restrict__ Wq, const float* __restrict__ Wk,
    const float* __restrict__ Wv,
    short* __restrict__ Xbf, short* __restrict__ Wbf)
{
    const int base = (blockIdx.x * 256 + threadIdx.x) * 4;
    const float* src; short* dst; int off;
    if (base < NHE)               { src = hidden; dst = Xbf;          off = base; }
    else if (base < NHE + WE)     { src = Wq;     dst = Wbf;          off = base - NHE; }
    else if (base < NHE + 2 * WE) { src = Wk;     dst = Wbf + WE;     off = base - NHE - WE; }
    else                          { src = Wv;     dst = Wbf + 2 * WE; off = base - NHE - 2 * WE; }
    f32x4 v = *reinterpret_cast<const f32x4*>(src + off);
    bf4 r;
    r[0] = f2bf(v[0]); r[1] = f2bf(v[1]); r[2] = f2bf(v[2]); r[3] = f2bf(v[3]);
    *reinterpret_cast<bf4*>(dst + off) = r;
}

// ---------------------------------------------------------------------------
// Kernel 1: QKV GEMM, LDS-staged (R7 version, unchanged).
// ---------------------------------------------------------------------------
__global__ __launch_bounds__(256, 3) void qkv_gemm(
    const short* __restrict__ Xbf, const short* __restrict__ Wbf,
    const float* __restrict__ bq, const float* __restrict__ bk,
    const float* __restrict__ bv,
    short* __restrict__ Qo, short* __restrict__ Ko, short* __restrict__ VTo)
{
    const int lane = threadIdx.x & 63;
    const int wave = threadIdx.x >> 6;
    const int lg = lane >> 4, lr = lane & 15;

    const int m0 = blockIdx.x * 128;
    const int n0 = blockIdx.y * 64;
    const int proj = n0 / NHID;
    const int ncol0 = n0 % NHID;
    const float* bias = proj == 0 ? bq : (proj == 1 ? bk : bv);

    __shared__ short Alds[2][128 * 64];
    __shared__ short Blds[2][64 * 64];

    f32x4 acc[2][4];
    #pragma unroll
    for (int mm = 0; mm < 2; ++mm)
        #pragma unroll
        for (int s = 0; s < 4; ++s) acc[mm][s] = (f32x4){0.f, 0.f, 0.f, 0.f};

    auto stage = [&](int t, int buf) {
        const int k0 = t * 64;
        #pragma unroll
        for (int p = 0; p < 4; ++p) {
            const int op = wave * 4 + p;
            const int unit = op * 64 + lane;
            const int r = unit >> 3, u = unit & 7;
            const int g = u ^ (r & 7);
            gld_lds16s(Xbf + (size_t)(m0 + r) * NHID + k0 + g * 8,
                       &Alds[buf][op * 512]);
        }
        #pragma unroll
        for (int p = 0; p < 2; ++p) {
            const int op = wave * 2 + p;
            const int unit = op * 64 + lane;
            const int r = unit >> 3, u = unit & 7;
            const int g = u ^ (r & 7);
            gld_lds16s(Wbf + (size_t)(n0 + r) * NHID + k0 + g * 8,
                       &Blds[buf][op * 512]);
        }
    };

    auto compute = [&](int buf) {
        #pragma unroll
        for (int kk = 0; kk < 2; ++kk) {
            const int U = kk * 4 + lg;
            short8 a[2];
            #pragma unroll
            for (int mm = 0; mm < 2; ++mm) {
                const int R = wave * 32 + mm * 16 + lr;
                a[mm] = *reinterpret_cast<const short8*>(
                    &Alds[buf][(R * 8 + (U ^ (R & 7))) * 8]);
            }
            #pragma unroll
            for (int s = 0; s < 4; ++s) {
                const int R = s * 16 + lr;
                short8 b = *reinterpret_cast<const short8*>(
                    &Blds[buf][(R * 8 + (U ^ (R & 7))) * 8]);
                acc[0][s] = MFMA(a[0], b, acc[0][s]);
                acc[1][s] = MFMA(a[1], b, acc[1][s]);
            }
        }
    };

    stage(0, 0);
    #pragma unroll 2
    for (int t = 0; t < 12; ++t) {
        const int buf = t & 1;
        asm volatile("s_waitcnt vmcnt(0)" ::: "memory");
        __syncthreads();
        if (t < 11) stage(t + 1, buf ^ 1);
        compute(buf);
    }

    #pragma unroll
    for (int mm = 0; mm < 2; ++mm) {
        #pragma unroll
        for (int s = 0; s < 4; ++s) {
            const int ncol = ncol0 + s * 16 + lr;
            const float badd = bias[ncol];
            #pragma unroll
            for (int r = 0; r < 4; ++r) {
                const int m = m0 + wave * 32 + mm * 16 + lg * 4 + r;
                const short v16 = f2bf(acc[mm][s][r] + badd);
                if (proj == 0) {
                    Qo[(size_t)m * NHID + ncol] = v16;
                } else if (proj == 1) {
                    Ko[(size_t)m * NHID + ncol] = v16;
                } else {
                    const int b = m >> 10, ss = m & 1023;
                    const int h = ncol >> 6, dd = ncol & 63;
                    VTo[(((size_t)(b * NHEAD + h) * NDH + dd) << 10) + ss] = v16;
                }
            }
        }
    }
}

// ---------------------------------------------------------------------------
// Kernel 2: bias GEMM -> bf16, pre-scaled + mask folded (R9 version).
// ---------------------------------------------------------------------------
__global__ __launch_bounds__(256, 2) void bias_gemm(
    const short* __restrict__ Q,
    const float* __restrict__ bbox,
    const float* __restrict__ mask,
    short* __restrict__ biasH)        // (2,12,1024,1024) bf16
{
    const int lane = threadIdx.x & 63;
    const int wave = threadIdx.x >> 6;
    const int lg = lane >> 4, lr = lane & 15;
    const int i = blockIdx.x;
    const int jq = wave * 256;

    __shared__ float lds[4][2][2048];

    short8 qa[2][2];
    #pragma unroll
    for (int b2 = 0; b2 < 2; ++b2)
        #pragma unroll
        for (int kk = 0; kk < 2; ++kk)
            qa[b2][kk] = *reinterpret_cast<const short8*>(
                Q + ((size_t)(b2 * NS) + i) * NHID + lr * 64 + kk * 32 + lg * 8);

    const int r_half = lane >> 5;
    const int u_lin = lane & 31;

    auto stage = [&](int t, int buf) {
        const int j0 = jq + t * 16;
        float* dst = &lds[wave][buf][0];
        #pragma unroll
        for (int w = 0; w < 8; ++w) {
            const int r = 2 * w + r_half;
            const int u = u_lin ^ (r & 7);
            const float* src = bbox + (size_t)(i * NS + j0 + r) * 128 + u * 4;
            gld_lds16(src, dst + w * 256);
        }
    };

    auto compute = [&](int t, int buf) {
        const float* tile = &lds[wave][buf][0];
        const int j0 = jq + t * 16;
        const int x = lr & 7;
        #pragma unroll
        for (int b2 = 0; b2 < 2; ++b2) {
            const float mk = mask[b2 * NS + j0 + lr];
            f32x4 c = (f32x4){0.f, 0.f, 0.f, 0.f};
            #pragma unroll
            for (int kk = 0; kk < 2; ++kk) {
                const int q0 = b2 * 16 + kk * 8 + lg * 2;
                f32x4 ca = *reinterpret_cast<const f32x4*>(tile + (size_t)(lr * 32 + ((q0)     ^ x)) * 4);
                f32x4 cb = *reinterpret_cast<const f32x4*>(tile + (size_t)(lr * 32 + ((q0 + 1) ^ x)) * 4);
                short8 bf;
                bf[0] = f2bf(ca[0]); bf[1] = f2bf(ca[1]); bf[2] = f2bf(ca[2]); bf[3] = f2bf(ca[3]);
                bf[4] = f2bf(cb[0]); bf[5] = f2bf(cb[1]); bf[6] = f2bf(cb[2]); bf[7] = f2bf(cb[3]);
                c = MFMA(qa[b2][kk], bf, c);
            }
            if (lg < 3) {
                #pragma unroll
                for (int r = 0; r < 4; ++r) {
                    const int n = lg * 4 + r;
                    biasH[((size_t)(b2 * NHEAD + n) * NS + i) * NS + j0 + lr] =
                        f2bf(c[r] * 0.125f + mk);
                }
            }
        }
    };

    stage(0, 0);
    for (int t = 0; t < 16; ++t) {
        const int buf = t & 1;
        asm volatile("s_waitcnt lgkmcnt(0)" ::: "memory");
        if (t < 15) stage(t + 1, buf ^ 1);
        if (t == 0 || t == 15) asm volatile("s_waitcnt vmcnt(8)"  ::: "memory");
        else                   asm volatile("s_waitcnt vmcnt(16)" ::: "memory");
        compute(t, buf);
    }
}

// ---------------------------------------------------------------------------
// Kernel 3: attention. K/V register-dbuf prefetch + bias tile loaded as ONE
// coalesced 16B/lane short8 into per-wave LDS dbuf (was 8 scattered 2B
// loads/tile -> fetch amplification). Static A/B buffers, no dyn indexing.
// ---------------------------------------------------------------------------
__global__ __launch_bounds__(256, 3) void attn2(
    const short* __restrict__ Q,
    const short* __restrict__ K,
    const short* __restrict__ VT,
    const short* __restrict__ biasH,
    float* __restrict__ out)
{
    const int lane = threadIdx.x & 63;
    const int wave = threadIdx.x >> 6;
    const int lg = lane >> 4, lr = lane & 15;
    const int i0 = blockIdx.x * 16;
    const int bh = blockIdx.y;
    const int b = bh / NHEAD, h = bh % NHEAD;
    const int jq = wave * 256;

    __shared__ short plds[4][16][40];
    __shared__ short blds[4][2][16 * 40];   // bias tile dbuf, 40-short rows (16B-aligned)
    __shared__ float numlds[4][16][68];
    __shared__ float denlds[4][16];

    short8 qa[2];
    #pragma unroll
    for (int kk = 0; kk < 2; ++kk)
        qa[kk] = *reinterpret_cast<const short8*>(
            Q + ((size_t)(b * NS) + i0 + lr) * NHID + h * 64 + kk * 32 + lg * 8);

    const short* Kb = K + (size_t)b * NS * NHID + h * 64;
    const short* Vb = VT + (size_t)(b * NHEAD + h) * NDH * NS;
    const short* Bb = biasH + ((size_t)(b * NHEAD + h) * NS + i0) * NS;

    f32x4 ctx[4];
    #pragma unroll
    for (int dt = 0; dt < 4; ++dt) ctx[dt] = (f32x4){0.f, 0.f, 0.f, 0.f};
    f32x4 den = (f32x4){0.f, 0.f, 0.f, 0.f};

    short8 kfA[4], vfA[4], bvA;
    short8 kfB[4], vfB[4], bvB;

    auto load = [&](int t, short8* kf, short8* vf, short8* bv) {
        const int j0 = jq + t * 32;
        #pragma unroll
        for (int s = 0; s < 2; ++s)
            #pragma unroll
            for (int kk = 0; kk < 2; ++kk)
                kf[s * 2 + kk] = *reinterpret_cast<const short8*>(
                    Kb + (size_t)(j0 + s * 16 + lr) * NHID + kk * 32 + lg * 8);
        #pragma unroll
        for (int dt = 0; dt < 4; ++dt)
            vf[dt] = *reinterpret_cast<const short8*>(
                Vb + (size_t)(dt * 16 + lr) * NS + j0 + lg * 8);
        // coalesced bias tile: lane -> (row=lane>>2, 8 j at (lane&3)*8)
        *bv = *reinterpret_cast<const short8*>(
            Bb + (size_t)(lane >> 2) * NS + j0 + (lane & 3) * 8);
    };

    auto storeB = [&](short8 bv, int buf) {
        *reinterpret_cast<short8*>(
            &blds[wave][buf][(lane >> 2) * 40 + (lane & 3) * 8]) = bv;
        asm volatile("" ::: "memory");
    };

    auto compute = [&](const short8* kf, const short8* vf, int buf) {
        f32x4 sc[2];
        #pragma unroll
        for (int s = 0; s < 2; ++s) {
            f32x4 c = (f32x4){0.f, 0.f, 0.f, 0.f};
            c = MFMA(qa[0], kf[s * 2 + 0], c);
            c = MFMA(qa[1], kf[s * 2 + 1], c);
            sc[s] = c;
        }
        #pragma unroll
        for (int s = 0; s < 2; ++s)
            #pragma unroll
            for (int r = 0; r < 4; ++r) {
                const unsigned int u = (unsigned int)(unsigned short)
                    blds[wave][buf][(lg * 4 + r) * 40 + s * 16 + lr] << 16;
                float bb;
                __builtin_memcpy(&bb, &u, 4);
                sc[s][r] = __expf(sc[s][r] * 0.125f + bb);
            }
        den += sc[0] + sc[1];

        #pragma unroll
        for (int s = 0; s < 2; ++s)
            #pragma unroll
            for (int r = 0; r < 4; ++r)
                plds[wave][lg * 4 + r][s * 16 + lr] = f2bf(sc[s][r]);
        asm volatile("" ::: "memory");
        short8 pa = *reinterpret_cast<const short8*>(&plds[wave][lr][lg * 8]);
        asm volatile("" ::: "memory");

        #pragma unroll
        for (int dt = 0; dt < 4; ++dt) ctx[dt] = MFMA(pa, vf[dt], ctx[dt]);
    };

    load(0, kfA, vfA, &bvA);
    #pragma unroll
    for (int tp = 0; tp < 4; ++tp) {
        const int t = tp * 2;
        storeB(bvA, 0);
        if (t + 1 < 8) load(t + 1, kfB, vfB, &bvB);
        compute(kfA, vfA, 0);
        storeB(bvB, 1);
        if (t + 2 < 8) load(t + 2, kfA, vfA, &bvA);
        compute(kfB, vfB, 1);
    }

    #pragma unroll
    for (int w = 1; w < 16; w <<= 1) {
        f32x4 o;
        #pragma unroll
        for (int r = 0; r < 4; ++r) o[r] = __shfl_xor(den[r], w, 64);
        den += o;
    }

    #pragma unroll
    for (int dt = 0; dt < 4; ++dt)
        #pragma unroll
        for (int r = 0; r < 4; ++r)
            numlds[wave][lg * 4 + r][dt * 16 + lr] = ctx[dt][r];
    if (lr == 0) {
        #pragma unroll
        for (int r = 0; r < 4; ++r) denlds[wave][lg * 4 + r] = den[r];
    }
    __syncthreads();

    const int ti = threadIdx.x >> 4;
    const int tc = (threadIdx.x & 15) * 4;
    f32x4 n = *reinterpret_cast<const f32x4*>(&numlds[0][ti][tc]);
    n += *reinterpret_cast<const f32x4*>(&numlds[1][ti][tc]);
    n += *reinterpret_cast<const f32x4*>(&numlds[2][ti][tc]);
    n += *reinterpret_cast<const f32x4*>(&numlds[3][ti][tc]);
    const float dd = denlds[0][ti] + denlds[1][ti] + denlds[2][ti] + denlds[3][ti];
    const float inv = 1.0f / dd;
    f32x4 o = n * inv;
    *reinterpret_cast<f32x4*>(out + ((size_t)(b * NS) + i0 + ti) * NHID + h * 64 + tc) = o;
}

extern "C" void kernel_launch(void* const* d_in, const int* in_sizes, int n_in,
                              void* d_out, int out_size, void* d_ws, size_t ws_size,
                              hipStream_t stream) {
    (void)in_sizes; (void)n_in; (void)out_size; (void)ws_size;
    const float* hidden = (const float*)d_in[0];
    const float* bbox   = (const float*)d_in[1];
    const float* mask   = (const float*)d_in[2];
    const float* Wq = (const float*)d_in[3]; const float* bq = (const float*)d_in[4];
    const float* Wk = (const float*)d_in[5]; const float* bk = (const float*)d_in[6];
    const float* Wv = (const float*)d_in[7]; const float* bv = (const float*)d_in[8];
    float* out = (float*)d_out;

    char* ws = (char*)d_ws;
    const size_t qkv_bytes = (size_t)NB * NS * NHID * sizeof(short);   // 3 MB each
    short* Qw  = (short*)ws;
    short* Kw  = (short*)(ws + qkv_bytes);
    short* VTw = (short*)(ws + 2 * qkv_bytes);
    short* biasH = (short*)(ws + 3 * qkv_bytes);                       // 50.3 MB bf16
    const size_t bias_bytes = (size_t)NB * NHEAD * NS * NS * sizeof(short);
    short* Xbf = (short*)(ws + 3 * qkv_bytes + bias_bytes);
    short* Wbf = Xbf + (size_t)2048 * NHID;

    const int cvt_total = (NHE + 3 * WE) / 4;
    cvt_bf16_all<<<cvt_total / 256, 256, 0, stream>>>(hidden, Wq, Wk, Wv, Xbf, Wbf);

    dim3 gp(16, 36);
    qkv_gemm<<<gp, 256, 0, stream>>>(Xbf, Wbf, bq, bk, bv, Qw, Kw, VTw);

    bias_gemm<<<NS, 256, 0, stream>>>(Qw, bbox, mask, biasH);

    dim3 ga(NS / 16, NB * NHEAD);
    attn2<<<ga, 256, 0, stream>>>(Qw, Kw, VTw, biasH, out);
}